// Round 4
// baseline (2038.204 us; speedup 1.0000x reference)
//
#include <hip/hip_runtime.h>
#include <hip/hip_fp16.h>

constexpr int TPB = 256;
constexpr int SH = 9;          // bucket = 512 consecutive destinations
constexpr int BD = 1 << SH;    // 512 dests per bucket (max 512 buckets -> n <= 262144)
constexpr int CHUNK = 4096;    // edges per binning block
constexpr int RMASK = (1 << 23) - 1;  // row in low 23 bits, local dest in high 9

typedef _Float16 half8 __attribute__((ext_vector_type(8)));
typedef float float4v __attribute__((ext_vector_type(4)));

__device__ __forceinline__ int wave_incl_scan(int x, int lane) {
#pragma unroll
  for (int d = 1; d < 64; d <<= 1) {
    int y = __shfl_up(x, d);
    if (lane >= d) x += y;
  }
  return x;
}

// ---------------- binned CSR build (grouped by destination) ----------------
// Edge entries are packed ints: (local_dest_in_bucket << 23) | src_row.
// n < 2^23 and BD = 512 -> fits exactly; halves the staging traffic vs int2
// and makes csr entries self-describing for the flat aggregation kernels.

__global__ void bin_kernel(const int* __restrict__ row, const int* __restrict__ col,
                           int* __restrict__ bcur, int* __restrict__ binned,
                           int e, int nb, int cap) {
  __shared__ int h[512];
  __shared__ int base[512];
  for (int i = threadIdx.x; i < nb; i += TPB) h[i] = 0;
  __syncthreads();
  int cb = blockIdx.x * CHUNK;
  int lim = min(cb + CHUNK, e);
  for (int i = cb + threadIdx.x; i < lim; i += TPB)
    atomicAdd(&h[col[i] >> SH], 1);
  __syncthreads();
  for (int i = threadIdx.x; i < nb; i += TPB) {
    int c = h[i];
    base[i] = c ? (i * cap + atomicAdd(&bcur[i], c)) : 0;
    h[i] = 0;  // reuse as local cursor
  }
  __syncthreads();
  for (int i = cb + threadIdx.x; i < lim; i += TPB) {
    int c = col[i];  // L2-hot re-read of this block's own chunk
    int b = c >> SH;
    int p = base[b] + atomicAdd(&h[b], 1);
    binned[p] = ((c & (BD - 1)) << 23) | row[i];
  }
}

// per bucket: fine counts -> scan -> offs2/dinv -> place (fused; binned stays L2-hot)
__global__ __launch_bounds__(512) void count_place_kernel(
    const int* __restrict__ binned, const int* __restrict__ bcnt, int cap,
    int2* __restrict__ offs2, float* __restrict__ dinv, int* __restrict__ csr, int n) {
  __shared__ int cnt[BD];
  __shared__ int wsum[8];
  int t = threadIdx.x, lane = t & 63, wv = t >> 6;
  int b = blockIdx.x;
  int c0 = b << SH;
  int ndst = min(BD, n - c0);
  cnt[t] = 0;
  __syncthreads();
  int beg = b * cap;
  int end = beg + bcnt[b];
  for (int i = beg + t; i < end; i += 512)
    atomicAdd(&cnt[(unsigned)binned[i] >> 23], 1);
  __syncthreads();
  int v = cnt[t];
  int ps = wave_incl_scan(v, lane);
  if (lane == 63) wsum[wv] = ps;
  __syncthreads();
  int woff = 0;
#pragma unroll
  for (int w = 0; w < 8; w++) woff += (w < wv) ? wsum[w] : 0;
  int ex = woff + ps - v;
  if (t < ndst) {
    offs2[c0 + t] = make_int2(beg + ex, beg + ex + v);
    dinv[c0 + t] = rsqrtf(1.0f + (float)v);  // deg = incoming + self-loop
  }
  __syncthreads();  // counts consumed; reuse cnt[] as cursors
  cnt[t] = beg + ex;
  __syncthreads();
  for (int i = beg + t; i < end; i += 512) {
    int pv = binned[i];
    int p = atomicAdd(&cnt[(unsigned)pv >> 23], 1);
    csr[p] = pv;  // packed entry passes through unchanged
  }
}

// ---------------- fused weight packing (+ bcur zero) ----------------

// Pack W[K,M] fp32 into B-fragment order for mfma_f32_16x16x32_f16:
// frag f = ct*KT+kt; lane holds B[k=kt*32+(lane>>4)*8+j][n=ct*16+(lane&15)].
template <int K, int M, int CT, int KT>
__device__ __forceinline__ void pack_one(const float* __restrict__ W,
                                         _Float16* __restrict__ P, int idx) {
  if (idx >= CT * KT * 64 * 8) return;
  int j = idx & 7;
  int lane = (idx >> 3) & 63;
  int f = idx >> 9;
  int kt = f % KT, ct = f / KT;
  int c = ct * 16 + (lane & 15);
  int k = kt * 32 + (lane >> 4) * 8 + j;
  float v = (c < M) ? W[k * M + c] : 0.f;
  P[idx] = (_Float16)v;
}

__global__ __launch_bounds__(256) void pack_all_kernel(
    const float* __restrict__ W1, const float* __restrict__ W2,
    const float* __restrict__ W3, _Float16* __restrict__ P1,
    _Float16* __restrict__ P2, _Float16* __restrict__ P3, int* __restrict__ bcur) {
  int blk = blockIdx.x, t = threadIdx.x;
  if (blk < 32) {
    pack_one<128, 64, 4, 4>(W1, P1, blk * 256 + t);
  } else if (blk < 48) {
    pack_one<64, 64, 4, 2>(W2, P2, (blk - 32) * 256 + t);
  } else if (blk < 60) {
    pack_one<64, 40, 3, 2>(W3, P3, (blk - 48) * 256 + t);
  } else {
    bcur[t] = 0;
    bcur[t + 256] = 0;
  }
}

// ---------------- layer-1 MFMA GEMM (fp32 in, fp16 out, dinv pre-scale) -----

template <int K, int M, int CT>
__global__ __launch_bounds__(256) void gemm_mfma_f32in(const float* __restrict__ x,
                                                       const _Float16* __restrict__ PW,
                                                       const float* __restrict__ dinv,
                                                       _Float16* __restrict__ out, int n) {
  constexpr int KT = K / 32;
  int lane = threadIdx.x & 63, wv = threadIdx.x >> 6;
  int m = lane & 15, q = lane >> 4;
  int row0w = blockIdx.x * 64 + wv * 16;
  int arow = row0w + m;
  int ar = arow < n ? arow : n - 1;  // clamp; stores are guarded
  const half8* pw = (const half8*)PW;

  float4v acc[CT];
#pragma unroll
  for (int ct = 0; ct < CT; ct++) acc[ct] = (float4v){0.f, 0.f, 0.f, 0.f};

#pragma unroll
  for (int kt = 0; kt < KT; kt++) {
    const float* xp = x + (size_t)ar * K + kt * 32 + q * 8;
    float4 x0 = *(const float4*)xp;
    float4 x1 = *(const float4*)(xp + 4);
    half8 a;
    a[0] = (_Float16)x0.x; a[1] = (_Float16)x0.y;
    a[2] = (_Float16)x0.z; a[3] = (_Float16)x0.w;
    a[4] = (_Float16)x1.x; a[5] = (_Float16)x1.y;
    a[6] = (_Float16)x1.z; a[7] = (_Float16)x1.w;
#pragma unroll
    for (int ct = 0; ct < CT; ct++) {
      half8 b = pw[(ct * KT + kt) * 64 + lane];
      acc[ct] = __builtin_amdgcn_mfma_f32_16x16x32_f16(a, b, acc[ct], 0, 0, 0);
    }
  }
  // D layout: col = lane&15, row = q*4 + reg
  int r0 = row0w + q * 4;
  float dv[4];
#pragma unroll
  for (int reg = 0; reg < 4; reg++) dv[reg] = (r0 + reg < n) ? dinv[r0 + reg] : 0.f;
#pragma unroll
  for (int ct = 0; ct < CT; ct++) {
    int c = ct * 16 + m;
    if (c < M) {
#pragma unroll
      for (int reg = 0; reg < 4; reg++) {
        int r = r0 + reg;
        if (r < n) out[(size_t)r * M + c] = (_Float16)(acc[ct][reg] * dv[reg]);
      }
    }
  }
}

// ---------------- flat aggregation (sorted-edge stream + LDS fp32 atomics) ---
// A block owns 64 consecutive dests = ONE contiguous csr range (csr is
// dest-sorted). 32 groups x 8 lanes stream contiguous sub-ranges: per edge,
// 8 lanes gather the full 128B source row (16B each) and ds_add_f32 into a
// fp32 LDS tile [64][65]. Iterations are independent -> deep MLP, no shfl,
// no dependent latency chains. Stride 65 spreads ds_add banks; adjacent
// groups sit ~2 dests apart so same-address atomic serialization is rare.

__device__ __forceinline__ void h8_unpack(uint4 u, float* f) {
  __half2 h0 = *(__half2*)&u.x, h1 = *(__half2*)&u.y;
  __half2 h2 = *(__half2*)&u.z, h3 = *(__half2*)&u.w;
  float2 f0 = __half22float2(h0), f1 = __half22float2(h1);
  float2 f2 = __half22float2(h2), f3 = __half22float2(h3);
  f[0] = f0.x; f[1] = f0.y; f[2] = f1.x; f[3] = f1.y;
  f[4] = f2.x; f[5] = f2.y; f[6] = f3.x; f[7] = f3.y;
}

__device__ __forceinline__ void agg_flat_phase(
    const uint4* __restrict__ xw4, const int* __restrict__ csr,
    const int2* __restrict__ offs2, float* __restrict__ tileF,
    int base, int n, int t) {
  for (int i = t; i < 64 * 65; i += TPB) tileF[i] = 0.f;
  __syncthreads();
  int grp = t >> 3, fl = t & 7;
  // self-loops (rows pre-scaled by their own dinv)
#pragma unroll
  for (int l = grp; l < 64; l += 32) {
    int i = base + l;
    if (i < n) {
      uint4 u = xw4[(size_t)i * 8 + fl];
      float f[8];
      h8_unpack(u, f);
      int a0 = l * 65 + fl * 8;
#pragma unroll
      for (int k = 0; k < 8; k++) atomicAdd(&tileF[a0 + k], f[k]);
    }
  }
  int lastd = min(base + 63, n - 1);
  int beg64 = offs2[base].x;
  int end64 = offs2[lastd].y;
  int E = end64 - beg64;
  int gb = beg64 + (E * grp) / 32;
  int ge = beg64 + (E * (grp + 1)) / 32;
  int boff = base & (BD - 1);
#pragma unroll 4
  for (int e2 = gb; e2 < ge; ++e2) {
    int v = csr[e2];
    int l = (int)((unsigned)v >> 23) - boff;
    int r = v & RMASK;
    uint4 u = xw4[(size_t)r * 8 + fl];
    float f[8];
    h8_unpack(u, f);
    int a0 = l * 65 + fl * 8;
#pragma unroll
    for (int k = 0; k < 8; k++) atomicAdd(&tileF[a0 + k], f[k]);
  }
  __syncthreads();
}

// ---------------- standalone mid aggregation (layer-2) ----------------
// out = relu(acc*di + b2) * di   (pre-scaled for the layer-3 pre-agg)

__global__ __launch_bounds__(256) void agg_mid_kernel(
    const uint4* __restrict__ xw4, const float* __restrict__ dinv,
    const int* __restrict__ csr, const int2* __restrict__ offs2,
    const float* __restrict__ bias, uint4* __restrict__ out4, int n) {
  __shared__ float tileF[64 * 65];
  int t = threadIdx.x;
  int base = blockIdx.x * 64;
  agg_flat_phase(xw4, csr, offs2, tileF, base, n, t);

  int l = t >> 2, c0 = (t & 3) * 16;
  int i = base + l;
  if (i < n) {
    float di = dinv[i];
    float o[16];
#pragma unroll
    for (int k = 0; k < 16; k++) {
      int c = c0 + k;
      o[k] = fmaxf(tileF[l * 65 + c] * di + bias[c], 0.f) * di;
    }
    uint4 u0, u1;
    {
      __half2 a = __float22half2_rn(make_float2(o[0], o[1]));
      __half2 b = __float22half2_rn(make_float2(o[2], o[3]));
      __half2 c = __float22half2_rn(make_float2(o[4], o[5]));
      __half2 d = __float22half2_rn(make_float2(o[6], o[7]));
      u0.x = *(unsigned*)&a; u0.y = *(unsigned*)&b;
      u0.z = *(unsigned*)&c; u0.w = *(unsigned*)&d;
    }
    {
      __half2 a = __float22half2_rn(make_float2(o[8], o[9]));
      __half2 b = __float22half2_rn(make_float2(o[10], o[11]));
      __half2 c = __float22half2_rn(make_float2(o[12], o[13]));
      __half2 d = __float22half2_rn(make_float2(o[14], o[15]));
      u1.x = *(unsigned*)&a; u1.y = *(unsigned*)&b;
      u1.z = *(unsigned*)&c; u1.w = *(unsigned*)&d;
    }
    out4[(size_t)i * 8 + (c0 >> 3)] = u0;
    out4[(size_t)i * 8 + (c0 >> 3) + 1] = u1;
  }
}

// ---------------- fused aggregation + MFMA GEMM ----------------
// Flat-agg into tileF, epilogue-convert into fp16 tileH (stride 72, 16B
// aligned rows for b128 reads), then 4 waves run the K=64 MFMA GEMM.
// FMODE 0 (layers 1->2): agg epilogue relu(acc*di + biasA); gemm out fp16 *dinv[r].
// FMODE 1 (layer 3):     agg epilogue acc*di;               gemm out fp32 + biasG.

template <int M, int CT, int FMODE>
__global__ __launch_bounds__(256) void fused_agg_gemm(
    const uint4* __restrict__ xw4, const float* __restrict__ dinv,
    const int* __restrict__ csr, const int2* __restrict__ offs2,
    const float* __restrict__ biasA, const float* __restrict__ biasG,
    const _Float16* __restrict__ PW, void* __restrict__ outp, int n) {
  constexpr int KT = 2;  // K = 64
  __shared__ float tileF[64 * 65];
  __shared__ _Float16 tileH[64 * 72];
  int t = threadIdx.x;
  int base = blockIdx.x * 64;
  agg_flat_phase(xw4, csr, offs2, tileF, base, n, t);

  {
    int l = t >> 2, c0 = (t & 3) * 16;
    int i = base + l;
    half8 h0 = (half8)(_Float16)0.f, h1 = (half8)(_Float16)0.f;
    if (i < n) {
      float di = dinv[i];
#pragma unroll
      for (int k = 0; k < 8; k++) {
        float f = tileF[l * 65 + c0 + k];
        f = (FMODE == 0) ? fmaxf(f * di + biasA[c0 + k], 0.f) : f * di;
        h0[k] = (_Float16)f;
      }
#pragma unroll
      for (int k = 0; k < 8; k++) {
        float f = tileF[l * 65 + c0 + 8 + k];
        f = (FMODE == 0) ? fmaxf(f * di + biasA[c0 + 8 + k], 0.f) : f * di;
        h1[k] = (_Float16)f;
      }
    }
    *(half8*)&tileH[l * 72 + c0] = h0;
    *(half8*)&tileH[l * 72 + c0 + 8] = h1;
  }
  __syncthreads();

  // ---- MFMA phase (same fragment mapping as the standalone GEMMs) ----
  int lane = t & 63, wv = t >> 6;
  int m = lane & 15, q = lane >> 4;
  int lrow = wv * 16 + m;
  const half8* pw = (const half8*)PW;
  float4v accd[CT];
#pragma unroll
  for (int ct = 0; ct < CT; ct++) accd[ct] = (float4v){0.f, 0.f, 0.f, 0.f};
#pragma unroll
  for (int kt = 0; kt < KT; kt++) {
    half8 a = *(const half8*)&tileH[lrow * 72 + kt * 32 + q * 8];
#pragma unroll
    for (int ct = 0; ct < CT; ct++) {
      half8 b = pw[(ct * KT + kt) * 64 + lane];
      accd[ct] = __builtin_amdgcn_mfma_f32_16x16x32_f16(a, b, accd[ct], 0, 0, 0);
    }
  }
  int r0 = base + wv * 16 + q * 4;
  if (FMODE == 0) {
    _Float16* out = (_Float16*)outp;
    float dv[4];
#pragma unroll
    for (int reg = 0; reg < 4; reg++) dv[reg] = (r0 + reg < n) ? dinv[r0 + reg] : 0.f;
#pragma unroll
    for (int ct = 0; ct < CT; ct++) {
      int c = ct * 16 + m;
      if (c < M) {
#pragma unroll
        for (int reg = 0; reg < 4; reg++) {
          int r = r0 + reg;
          if (r < n) out[(size_t)r * M + c] = (_Float16)(accd[ct][reg] * dv[reg]);
        }
      }
    }
  } else {
    float* out = (float*)outp;
#pragma unroll
    for (int ct = 0; ct < CT; ct++) {
      int c = ct * 16 + m;
      if (c < M) {
        float bb = biasG[c];
#pragma unroll
        for (int reg = 0; reg < 4; reg++) {
          int r = r0 + reg;
          if (r < n) out[(size_t)r * M + c] = accd[ct][reg] + bb;
        }
      }
    }
  }
}

// ---------------- launcher ----------------

extern "C" void kernel_launch(void* const* d_in, const int* in_sizes, int n_in,
                              void* d_out, int out_size, void* d_ws, size_t ws_size,
                              hipStream_t stream) {
  const float* x  = (const float*)d_in[0];
  const int*   ei = (const int*)d_in[1];
  const float* W1 = (const float*)d_in[2];
  const float* b1 = (const float*)d_in[3];
  const float* W2 = (const float*)d_in[4];
  const float* b2 = (const float*)d_in[5];
  const float* W3 = (const float*)d_in[6];
  const float* b3 = (const float*)d_in[7];

  int n = in_sizes[0] / 128;
  int e = in_sizes[1] / 2;
  const int* rowA = ei;      // edge_index[0] = source
  const int* colA = ei + e;  // edge_index[1] = destination (segment id)

  int nb = (n + BD - 1) >> SH;  // buckets (<= 512)
  int meanb = e / nb;
  int cap = meanb + (meanb / 4 > 1024 ? meanb / 4 : 1024);  // >25 sigma slack
  int nch = (e + CHUNK - 1) / CHUNK;

  size_t off = 0;
  auto alloc = [&](size_t bytes) {
    void* p = (char*)d_ws + off;
    off += (bytes + 255) & ~(size_t)255;
    return p;
  };
  // bufA (n*64*4 B) also aliases the binned edge array (nb*cap*4 <= n*103 B)
  __half* bufA  = (__half*)alloc((size_t)n * 64 * 4);
  __half* bufB  = (__half*)alloc((size_t)n * 64 * 4);
  int2*  offs2  = (int2*)alloc((size_t)n * 8);
  float* dinv   = (float*)alloc((size_t)n * 4);
  int*   csr    = (int*)alloc((size_t)nb * cap * 4);
  int*   bcur   = (int*)alloc(512 * 4);
  _Float16* PW1 = (_Float16*)alloc(4 * 4 * 64 * 8 * 2);  // CT=4, KT=4
  _Float16* PW2 = (_Float16*)alloc(4 * 2 * 64 * 8 * 2);  // CT=4, KT=2
  _Float16* PW3 = (_Float16*)alloc(3 * 2 * 64 * 8 * 2);  // CT=3, KT=2
  int*   binned = (int*)bufA;  // consumed by count_place before gemm1 writes bufA
  (void)ws_size; (void)n_in; (void)out_size;

  // fused: pack all three W matrices + zero bcur (one dispatch)
  pack_all_kernel<<<61, TPB, 0, stream>>>(W1, W2, W3, PW1, PW2, PW3, bcur);
  bin_kernel<<<nch, TPB, 0, stream>>>(rowA, colA, bcur, binned, e, nb, cap);
  count_place_kernel<<<nb, 512, 0, stream>>>(binned, bcur, cap, offs2, dinv, csr, n);

  int gmf = (n + 63) / 64;  // 64 dest rows per block everywhere

  // L1 GEMM: bufA = (x @ W1) * dinv[row]
  gemm_mfma_f32in<128, 64, 4><<<gmf, TPB, 0, stream>>>(x, PW1, dinv, (_Float16*)bufA, n);
  // agg0 + gemm2 fused: bufB = (relu(L(bufA) + b1) @ W2) * dinv[row]
  fused_agg_gemm<64, 4, 0><<<gmf, TPB, 0, stream>>>(
      (const uint4*)bufA, dinv, csr, offs2, b1, nullptr, PW2, bufB, n);
  // agg1: bufA = relu(L(bufB) + b2) * dinv[row]
  agg_mid_kernel<<<gmf, TPB, 0, stream>>>((const uint4*)bufB, dinv, csr, offs2,
                                          b2, (uint4*)bufA, n);
  // agg2 + gemm3 fused: out = L(bufA) @ W3 + b3  (fp32)
  fused_agg_gemm<40, 3, 1><<<gmf, TPB, 0, stream>>>(
      (const uint4*)bufA, dinv, csr, offs2, nullptr, b3, PW3, d_out, n);
}

// Round 5
// 345.227 us; speedup vs baseline: 5.9040x; 5.9040x over previous
//
#include <hip/hip_runtime.h>
#include <hip/hip_fp16.h>

constexpr int TPB = 256;
constexpr int SH = 9;          // bucket = 512 consecutive destinations
constexpr int BD = 1 << SH;    // 512 dests per bucket (max 512 buckets -> n <= 262144)
constexpr int CHUNK = 4096;    // edges per binning block
constexpr int RMASK = (1 << 23) - 1;  // row in low 23 bits, local dest in high 9

typedef _Float16 half8 __attribute__((ext_vector_type(8)));
typedef float float4v __attribute__((ext_vector_type(4)));

__device__ __forceinline__ int wave_incl_scan(int x, int lane) {
#pragma unroll
  for (int d = 1; d < 64; d <<= 1) {
    int y = __shfl_up(x, d);
    if (lane >= d) x += y;
  }
  return x;
}

// ---------------- binned CSR build (grouped by destination) ----------------
// Edge entries are packed ints: (local_dest_in_bucket << 23) | src_row.

__global__ void bin_kernel(const int* __restrict__ row, const int* __restrict__ col,
                           int* __restrict__ bcur, int* __restrict__ binned,
                           int e, int nb, int cap) {
  __shared__ int h[512];
  __shared__ int base[512];
  for (int i = threadIdx.x; i < nb; i += TPB) h[i] = 0;
  __syncthreads();
  int cb = blockIdx.x * CHUNK;
  int lim = min(cb + CHUNK, e);
  for (int i = cb + threadIdx.x; i < lim; i += TPB)
    atomicAdd(&h[col[i] >> SH], 1);
  __syncthreads();
  for (int i = threadIdx.x; i < nb; i += TPB) {
    int c = h[i];
    base[i] = c ? (i * cap + atomicAdd(&bcur[i], c)) : 0;
    h[i] = 0;  // reuse as local cursor
  }
  __syncthreads();
  for (int i = cb + threadIdx.x; i < lim; i += TPB) {
    int c = col[i];  // L2-hot re-read of this block's own chunk
    int b = c >> SH;
    int p = base[b] + atomicAdd(&h[b], 1);
    binned[p] = ((c & (BD - 1)) << 23) | row[i];
  }
}

// per bucket: fine counts -> scan -> offs2/dinv -> place (fused; binned stays L2-hot)
__global__ __launch_bounds__(512) void count_place_kernel(
    const int* __restrict__ binned, const int* __restrict__ bcnt, int cap,
    int2* __restrict__ offs2, float* __restrict__ dinv, int* __restrict__ csr, int n) {
  __shared__ int cnt[BD];
  __shared__ int wsum[8];
  int t = threadIdx.x, lane = t & 63, wv = t >> 6;
  int b = blockIdx.x;
  int c0 = b << SH;
  int ndst = min(BD, n - c0);
  cnt[t] = 0;
  __syncthreads();
  int beg = b * cap;
  int end = beg + bcnt[b];
  for (int i = beg + t; i < end; i += 512)
    atomicAdd(&cnt[(unsigned)binned[i] >> 23], 1);
  __syncthreads();
  int v = cnt[t];
  int ps = wave_incl_scan(v, lane);
  if (lane == 63) wsum[wv] = ps;
  __syncthreads();
  int woff = 0;
#pragma unroll
  for (int w = 0; w < 8; w++) woff += (w < wv) ? wsum[w] : 0;
  int ex = woff + ps - v;
  if (t < ndst) {
    offs2[c0 + t] = make_int2(beg + ex, beg + ex + v);
    dinv[c0 + t] = rsqrtf(1.0f + (float)v);  // deg = incoming + self-loop
  }
  __syncthreads();  // counts consumed; reuse cnt[] as cursors
  cnt[t] = beg + ex;
  __syncthreads();
  for (int i = beg + t; i < end; i += 512) {
    int pv = binned[i];
    int p = atomicAdd(&cnt[(unsigned)pv >> 23], 1);
    csr[p] = pv;  // packed entry passes through unchanged
  }
}

// ---------------- fused weight packing (+ bcur zero) ----------------

template <int K, int M, int CT, int KT>
__device__ __forceinline__ void pack_one(const float* __restrict__ W,
                                         _Float16* __restrict__ P, int idx) {
  if (idx >= CT * KT * 64 * 8) return;
  int j = idx & 7;
  int lane = (idx >> 3) & 63;
  int f = idx >> 9;
  int kt = f % KT, ct = f / KT;
  int c = ct * 16 + (lane & 15);
  int k = kt * 32 + (lane >> 4) * 8 + j;
  float v = (c < M) ? W[k * M + c] : 0.f;
  P[idx] = (_Float16)v;
}

__global__ __launch_bounds__(256) void pack_all_kernel(
    const float* __restrict__ W1, const float* __restrict__ W2,
    const float* __restrict__ W3, _Float16* __restrict__ P1,
    _Float16* __restrict__ P2, _Float16* __restrict__ P3, int* __restrict__ bcur) {
  int blk = blockIdx.x, t = threadIdx.x;
  if (blk < 32) {
    pack_one<128, 64, 4, 4>(W1, P1, blk * 256 + t);
  } else if (blk < 48) {
    pack_one<64, 64, 4, 2>(W2, P2, (blk - 32) * 256 + t);
  } else if (blk < 60) {
    pack_one<64, 40, 3, 2>(W3, P3, (blk - 48) * 256 + t);
  } else {
    bcur[t] = 0;
    bcur[t + 256] = 0;
  }
}

// ---------------- layer-1 MFMA GEMM (fp32 in, fp16 out, dinv pre-scale) -----

template <int K, int M, int CT>
__global__ __launch_bounds__(256) void gemm_mfma_f32in(const float* __restrict__ x,
                                                       const _Float16* __restrict__ PW,
                                                       const float* __restrict__ dinv,
                                                       _Float16* __restrict__ out, int n) {
  constexpr int KT = K / 32;
  int lane = threadIdx.x & 63, wv = threadIdx.x >> 6;
  int m = lane & 15, q = lane >> 4;
  int row0w = blockIdx.x * 64 + wv * 16;
  int arow = row0w + m;
  int ar = arow < n ? arow : n - 1;  // clamp; stores are guarded
  const half8* pw = (const half8*)PW;

  float4v acc[CT];
#pragma unroll
  for (int ct = 0; ct < CT; ct++) acc[ct] = (float4v){0.f, 0.f, 0.f, 0.f};

#pragma unroll
  for (int kt = 0; kt < KT; kt++) {
    const float* xp = x + (size_t)ar * K + kt * 32 + q * 8;
    float4 x0 = *(const float4*)xp;
    float4 x1 = *(const float4*)(xp + 4);
    half8 a;
    a[0] = (_Float16)x0.x; a[1] = (_Float16)x0.y;
    a[2] = (_Float16)x0.z; a[3] = (_Float16)x0.w;
    a[4] = (_Float16)x1.x; a[5] = (_Float16)x1.y;
    a[6] = (_Float16)x1.z; a[7] = (_Float16)x1.w;
#pragma unroll
    for (int ct = 0; ct < CT; ct++) {
      half8 b = pw[(ct * KT + kt) * 64 + lane];
      acc[ct] = __builtin_amdgcn_mfma_f32_16x16x32_f16(a, b, acc[ct], 0, 0, 0);
    }
  }
  // D layout: col = lane&15, row = q*4 + reg
  int r0 = row0w + q * 4;
  float dv[4];
#pragma unroll
  for (int reg = 0; reg < 4; reg++) dv[reg] = (r0 + reg < n) ? dinv[r0 + reg] : 0.f;
#pragma unroll
  for (int ct = 0; ct < CT; ct++) {
    int c = ct * 16 + m;
    if (c < M) {
#pragma unroll
      for (int reg = 0; reg < 4; reg++) {
        int r = r0 + reg;
        if (r < n) out[(size_t)r * M + c] = (_Float16)(acc[ct][reg] * dv[reg]);
      }
    }
  }
}

// ---------------- flat aggregation, ATOMIC-FREE ----------------
// Block owns 64 consecutive dests = one contiguous csr range (dest-sorted).
// Group boundaries are SNAPPED TO DEST BOUNDARIES (binary search over the
// dbeg[] LDS table), so each dest's whole edge run belongs to exactly one
// 8-lane group: accumulate in registers, flush with plain ds_write_b128 x2
// (exclusive owner -> no atomics, no RMW). Self-loop is added in the
// epilogue from a coalesced re-read of the node's own (pre-scaled) row.
// tileF stride 68 floats keeps flushes 16B-aligned.

__device__ __forceinline__ void h8_unpack(uint4 u, float* f) {
  __half2 h0 = *(__half2*)&u.x, h1 = *(__half2*)&u.y;
  __half2 h2 = *(__half2*)&u.z, h3 = *(__half2*)&u.w;
  float2 f0 = __half22float2(h0), f1 = __half22float2(h1);
  float2 f2 = __half22float2(h2), f3 = __half22float2(h3);
  f[0] = f0.x; f[1] = f0.y; f[2] = f1.x; f[3] = f1.y;
  f[4] = f2.x; f[5] = f2.y; f[6] = f3.x; f[7] = f3.y;
}

__device__ __forceinline__ uint4 pack_h8v(const float* o) {
  __half2 h0 = __float22half2_rn(make_float2(o[0], o[1]));
  __half2 h1 = __float22half2_rn(make_float2(o[2], o[3]));
  __half2 h2 = __float22half2_rn(make_float2(o[4], o[5]));
  __half2 h3 = __float22half2_rn(make_float2(o[6], o[7]));
  uint4 u;
  u.x = *(unsigned*)&h0;
  u.y = *(unsigned*)&h1;
  u.z = *(unsigned*)&h2;
  u.w = *(unsigned*)&h3;
  return u;
}

__device__ __forceinline__ int lb_dbeg(const int* __restrict__ dbeg, int s) {
  int lo = 0, hi = 64;
  while (lo < hi) {
    int mid = (lo + hi) >> 1;
    if (dbeg[mid] < s) lo = mid + 1; else hi = mid;
  }
  return lo;  // smallest j in [0,64] with dbeg[j] >= s
}

__device__ __forceinline__ void agg_edge_phase(
    const uint4* __restrict__ xw4, const int* __restrict__ csr,
    float* __restrict__ tileF, const int* __restrict__ dbeg,
    int beg64, int E, int boff, int t) {
  int grp = t >> 3, fl = t & 7;
  int s0 = beg64 + (E * grp) / 32;
  int s1 = beg64 + (E * (grp + 1)) / 32;
  int b0 = dbeg[lb_dbeg(dbeg, s0)];  // snapped to dest boundaries
  int b1 = dbeg[lb_dbeg(dbeg, s1)];
  float4 accA = {0.f, 0.f, 0.f, 0.f}, accB = {0.f, 0.f, 0.f, 0.f};
  int lcur = -1;
  for (int e2 = b0; e2 < b1; ++e2) {
    int v = csr[e2];                       // group-uniform (8-lane broadcast)
    int l = (int)((unsigned)v >> 23) - boff;
    if (l != lcur) {                       // group-uniform branch
      if (lcur >= 0) {
        *(float4*)&tileF[lcur * 68 + fl * 8] = accA;
        *(float4*)&tileF[lcur * 68 + fl * 8 + 4] = accB;
      }
      lcur = l;
      accA = (float4){0.f, 0.f, 0.f, 0.f};
      accB = (float4){0.f, 0.f, 0.f, 0.f};
    }
    uint4 u = xw4[(size_t)(v & RMASK) * 8 + fl];  // 8 lanes = full 128B row
    float f[8];
    h8_unpack(u, f);
    accA.x += f[0]; accA.y += f[1]; accA.z += f[2]; accA.w += f[3];
    accB.x += f[4]; accB.y += f[5]; accB.z += f[6]; accB.w += f[7];
  }
  if (lcur >= 0) {
    *(float4*)&tileF[lcur * 68 + fl * 8] = accA;
    *(float4*)&tileF[lcur * 68 + fl * 8 + 4] = accB;
  }
}

// shared setup: zero tileF, fill dbeg[65]; returns (beg64, E) via refs
__device__ __forceinline__ void agg_setup(
    const int2* __restrict__ offs2, float* __restrict__ tileF,
    int* __restrict__ dbeg, int base, int n, int t, int& beg64, int& E) {
  int lastd = min(base + 63, n - 1);
  int end64 = offs2[lastd].y;
  beg64 = offs2[base].x;
  E = end64 - beg64;
  for (int i2 = t; i2 < 64 * 68; i2 += TPB) tileF[i2] = 0.f;
  if (t < 64) {
    int i = base + t;
    dbeg[t] = (i < n) ? offs2[i].x : end64;
  }
  if (t == 0) dbeg[64] = end64;
  __syncthreads();
}

// ---------------- standalone mid aggregation (layer-2) ----------------
// out = relu((acc+self)*di + b2) * di   (pre-scaled for the layer-3 pre-agg)

__global__ __launch_bounds__(256) void agg_mid_kernel(
    const uint4* __restrict__ xw4, const float* __restrict__ dinv,
    const int* __restrict__ csr, const int2* __restrict__ offs2,
    const float* __restrict__ bias, uint4* __restrict__ out4, int n) {
  __shared__ float tileF[64 * 68];
  __shared__ int dbeg[65];
  int t = threadIdx.x;
  int base = blockIdx.x * 64;
  int beg64, E;
  agg_setup(offs2, tileF, dbeg, base, n, t, beg64, E);
  agg_edge_phase(xw4, csr, tileF, dbeg, beg64, E, base & (BD - 1), t);
  __syncthreads();

  for (int s = t; s < 512; s += TPB) {
    int l = s >> 3, ch = s & 7;  // row l, 8-float chunk ch (coalesced stores)
    int i = base + l;
    if (i < n) {
      float di = dinv[i];
      uint4 sv = xw4[(size_t)i * 8 + ch];  // self-loop (pre-scaled row)
      float sf[8];
      h8_unpack(sv, sf);
      float o[8];
#pragma unroll
      for (int k = 0; k < 8; k++) {
        int c = ch * 8 + k;
        o[k] = fmaxf((tileF[l * 68 + c] + sf[k]) * di + bias[c], 0.f) * di;
      }
      out4[(size_t)i * 8 + ch] = pack_h8v(o);
    }
  }
}

// ---------------- fused aggregation + MFMA GEMM ----------------
// Flat-agg into tileF, epilogue-convert (+self row) into fp16 tileH (stride
// 72, 16B-aligned rows), then 4 waves run the K=64 MFMA GEMM from LDS.
// FMODE 0 (layers 1->2): agg epilogue relu(acc*di + biasA); gemm out fp16 *dinv[r].
// FMODE 1 (layer 3):     agg epilogue acc*di;               gemm out fp32 + biasG.

template <int M, int CT, int FMODE>
__global__ __launch_bounds__(256) void fused_agg_gemm(
    const uint4* __restrict__ xw4, const float* __restrict__ dinv,
    const int* __restrict__ csr, const int2* __restrict__ offs2,
    const float* __restrict__ biasA, const float* __restrict__ biasG,
    const _Float16* __restrict__ PW, void* __restrict__ outp, int n) {
  constexpr int KT = 2;  // K = 64
  __shared__ float tileF[64 * 68];
  __shared__ _Float16 tileH[64 * 72];
  __shared__ int dbeg[65];
  int t = threadIdx.x;
  int base = blockIdx.x * 64;
  int beg64, E;
  agg_setup(offs2, tileF, dbeg, base, n, t, beg64, E);
  agg_edge_phase(xw4, csr, tileF, dbeg, beg64, E, base & (BD - 1), t);
  __syncthreads();

  for (int s = t; s < 512; s += TPB) {
    int l = s >> 3, ch = s & 7;
    int i = base + l;
    half8 h = (half8)(_Float16)0.f;
    if (i < n) {
      float di = dinv[i];
      uint4 sv = xw4[(size_t)i * 8 + ch];  // self-loop row (pre-scaled)
      float sf[8];
      h8_unpack(sv, sf);
#pragma unroll
      for (int k = 0; k < 8; k++) {
        int c = ch * 8 + k;
        float f = tileF[l * 68 + c] + sf[k];
        f = (FMODE == 0) ? fmaxf(f * di + biasA[c], 0.f) : f * di;
        h[k] = (_Float16)f;
      }
    }
    *(half8*)&tileH[l * 72 + ch * 8] = h;
  }
  __syncthreads();

  // ---- MFMA phase (same fragment mapping as the standalone GEMMs) ----
  int lane = t & 63, wv = t >> 6;
  int m = lane & 15, q = lane >> 4;
  int lrow = wv * 16 + m;
  const half8* pw = (const half8*)PW;
  float4v accd[CT];
#pragma unroll
  for (int ct = 0; ct < CT; ct++) accd[ct] = (float4v){0.f, 0.f, 0.f, 0.f};
#pragma unroll
  for (int kt = 0; kt < KT; kt++) {
    half8 a = *(const half8*)&tileH[lrow * 72 + kt * 32 + q * 8];
#pragma unroll
    for (int ct = 0; ct < CT; ct++) {
      half8 b = pw[(ct * KT + kt) * 64 + lane];
      accd[ct] = __builtin_amdgcn_mfma_f32_16x16x32_f16(a, b, accd[ct], 0, 0, 0);
    }
  }
  int r0 = base + wv * 16 + q * 4;
  if (FMODE == 0) {
    _Float16* out = (_Float16*)outp;
    float dv[4];
#pragma unroll
    for (int reg = 0; reg < 4; reg++) dv[reg] = (r0 + reg < n) ? dinv[r0 + reg] : 0.f;
#pragma unroll
    for (int ct = 0; ct < CT; ct++) {
      int c = ct * 16 + m;
      if (c < M) {
#pragma unroll
        for (int reg = 0; reg < 4; reg++) {
          int r = r0 + reg;
          if (r < n) out[(size_t)r * M + c] = (_Float16)(accd[ct][reg] * dv[reg]);
        }
      }
    }
  } else {
    float* out = (float*)outp;
#pragma unroll
    for (int ct = 0; ct < CT; ct++) {
      int c = ct * 16 + m;
      if (c < M) {
        float bb = biasG[c];
#pragma unroll
        for (int reg = 0; reg < 4; reg++) {
          int r = r0 + reg;
          if (r < n) out[(size_t)r * M + c] = accd[ct][reg] + bb;
        }
      }
    }
  }
}

// ---------------- launcher ----------------

extern "C" void kernel_launch(void* const* d_in, const int* in_sizes, int n_in,
                              void* d_out, int out_size, void* d_ws, size_t ws_size,
                              hipStream_t stream) {
  const float* x  = (const float*)d_in[0];
  const int*   ei = (const int*)d_in[1];
  const float* W1 = (const float*)d_in[2];
  const float* b1 = (const float*)d_in[3];
  const float* W2 = (const float*)d_in[4];
  const float* b2 = (const float*)d_in[5];
  const float* W3 = (const float*)d_in[6];
  const float* b3 = (const float*)d_in[7];

  int n = in_sizes[0] / 128;
  int e = in_sizes[1] / 2;
  const int* rowA = ei;      // edge_index[0] = source
  const int* colA = ei + e;  // edge_index[1] = destination (segment id)

  int nb = (n + BD - 1) >> SH;  // buckets (<= 512)
  int meanb = e / nb;
  int cap = meanb + (meanb / 4 > 1024 ? meanb / 4 : 1024);  // >25 sigma slack
  int nch = (e + CHUNK - 1) / CHUNK;

  size_t off = 0;
  auto alloc = [&](size_t bytes) {
    void* p = (char*)d_ws + off;
    off += (bytes + 255) & ~(size_t)255;
    return p;
  };
  // bufA (n*64*4 B) also aliases the binned edge array (nb*cap*4 <= n*103 B)
  __half* bufA  = (__half*)alloc((size_t)n * 64 * 4);
  __half* bufB  = (__half*)alloc((size_t)n * 64 * 4);
  int2*  offs2  = (int2*)alloc((size_t)n * 8);
  float* dinv   = (float*)alloc((size_t)n * 4);
  int*   csr    = (int*)alloc((size_t)nb * cap * 4);
  int*   bcur   = (int*)alloc(512 * 4);
  _Float16* PW1 = (_Float16*)alloc(4 * 4 * 64 * 8 * 2);  // CT=4, KT=4
  _Float16* PW2 = (_Float16*)alloc(4 * 2 * 64 * 8 * 2);  // CT=4, KT=2
  _Float16* PW3 = (_Float16*)alloc(3 * 2 * 64 * 8 * 2);  // CT=3, KT=2
  int*   binned = (int*)bufA;  // consumed by count_place before gemm1 writes bufA
  (void)ws_size; (void)n_in; (void)out_size;

  // fused: pack all three W matrices + zero bcur (one dispatch)
  pack_all_kernel<<<61, TPB, 0, stream>>>(W1, W2, W3, PW1, PW2, PW3, bcur);
  bin_kernel<<<nch, TPB, 0, stream>>>(rowA, colA, bcur, binned, e, nb, cap);
  count_place_kernel<<<nb, 512, 0, stream>>>(binned, bcur, cap, offs2, dinv, csr, n);

  int gmf = (n + 63) / 64;  // 64 dest rows per block everywhere

  // L1 GEMM: bufA = (x @ W1) * dinv[row]
  gemm_mfma_f32in<128, 64, 4><<<gmf, TPB, 0, stream>>>(x, PW1, dinv, (_Float16*)bufA, n);
  // agg0 + gemm2 fused: bufB = (relu(L(bufA) + b1) @ W2) * dinv[row]
  fused_agg_gemm<64, 4, 0><<<gmf, TPB, 0, stream>>>(
      (const uint4*)bufA, dinv, csr, offs2, b1, nullptr, PW2, bufB, n);
  // agg1: bufA = relu(L(bufB) + b2) * dinv[row]
  agg_mid_kernel<<<gmf, TPB, 0, stream>>>((const uint4*)bufB, dinv, csr, offs2,
                                          b2, (uint4*)bufA, n);
  // agg2 + gemm3 fused: out = L(bufA) @ W3 + b3  (fp32)
  fused_agg_gemm<40, 3, 1><<<gmf, TPB, 0, stream>>>(
      (const uint4*)bufA, dinv, csr, offs2, nullptr, b3, PW3, d_out, n);
}

// Round 6
// 323.034 us; speedup vs baseline: 6.3096x; 1.0687x over previous
//
#include <hip/hip_runtime.h>
#include <hip/hip_fp16.h>

constexpr int TPB = 256;
constexpr int SH = 9;          // bucket = 512 consecutive destinations
constexpr int BD = 1 << SH;    // 512 dests per bucket (max 512 buckets -> n <= 262144)
constexpr int CHUNK = 4096;    // edges per binning block
constexpr int RMASK = (1 << 23) - 1;  // row in low 23 bits, local dest in high 9

typedef _Float16 half8 __attribute__((ext_vector_type(8)));
typedef float float4v __attribute__((ext_vector_type(4)));

__device__ __forceinline__ int wave_incl_scan(int x, int lane) {
#pragma unroll
  for (int d = 1; d < 64; d <<= 1) {
    int y = __shfl_up(x, d);
    if (lane >= d) x += y;
  }
  return x;
}

// ---------------- binned CSR build (grouped by destination) ----------------
// Edge entries are packed ints: (local_dest_in_bucket << 23) | src_row.

__global__ void bin_kernel(const int* __restrict__ row, const int* __restrict__ col,
                           int* __restrict__ bcur, int* __restrict__ binned,
                           int e, int nb, int cap) {
  __shared__ int h[512];
  __shared__ int base[512];
  for (int i = threadIdx.x; i < nb; i += TPB) h[i] = 0;
  __syncthreads();
  int cb = blockIdx.x * CHUNK;
  int lim = min(cb + CHUNK, e);
  for (int i = cb + threadIdx.x; i < lim; i += TPB)
    atomicAdd(&h[col[i] >> SH], 1);
  __syncthreads();
  for (int i = threadIdx.x; i < nb; i += TPB) {
    int c = h[i];
    base[i] = c ? (i * cap + atomicAdd(&bcur[i], c)) : 0;
    h[i] = 0;  // reuse as local cursor
  }
  __syncthreads();
  for (int i = cb + threadIdx.x; i < lim; i += TPB) {
    int c = col[i];  // L2-hot re-read of this block's own chunk
    int b = c >> SH;
    int p = base[b] + atomicAdd(&h[b], 1);
    binned[p] = ((c & (BD - 1)) << 23) | row[i];
  }
}

// per bucket: fine counts -> scan -> offs2/dinv -> place (fused; binned stays L2-hot)
__global__ __launch_bounds__(512) void count_place_kernel(
    const int* __restrict__ binned, const int* __restrict__ bcnt, int cap,
    int2* __restrict__ offs2, float* __restrict__ dinv, int* __restrict__ csr, int n) {
  __shared__ int cnt[BD];
  __shared__ int wsum[8];
  int t = threadIdx.x, lane = t & 63, wv = t >> 6;
  int b = blockIdx.x;
  int c0 = b << SH;
  int ndst = min(BD, n - c0);
  cnt[t] = 0;
  __syncthreads();
  int beg = b * cap;
  int end = beg + bcnt[b];
  for (int i = beg + t; i < end; i += 512)
    atomicAdd(&cnt[(unsigned)binned[i] >> 23], 1);
  __syncthreads();
  int v = cnt[t];
  int ps = wave_incl_scan(v, lane);
  if (lane == 63) wsum[wv] = ps;
  __syncthreads();
  int woff = 0;
#pragma unroll
  for (int w = 0; w < 8; w++) woff += (w < wv) ? wsum[w] : 0;
  int ex = woff + ps - v;
  if (t < ndst) {
    offs2[c0 + t] = make_int2(beg + ex, beg + ex + v);
    dinv[c0 + t] = rsqrtf(1.0f + (float)v);  // deg = incoming + self-loop
  }
  __syncthreads();  // counts consumed; reuse cnt[] as cursors
  cnt[t] = beg + ex;
  __syncthreads();
  for (int i = beg + t; i < end; i += 512) {
    int pv = binned[i];
    int p = atomicAdd(&cnt[(unsigned)pv >> 23], 1);
    csr[p] = pv;  // packed entry passes through unchanged
  }
}

// ---------------- fused weight packing (+ bcur zero) ----------------

template <int K, int M, int CT, int KT>
__device__ __forceinline__ void pack_one(const float* __restrict__ W,
                                         _Float16* __restrict__ P, int idx) {
  if (idx >= CT * KT * 64 * 8) return;
  int j = idx & 7;
  int lane = (idx >> 3) & 63;
  int f = idx >> 9;
  int kt = f % KT, ct = f / KT;
  int c = ct * 16 + (lane & 15);
  int k = kt * 32 + (lane >> 4) * 8 + j;
  float v = (c < M) ? W[k * M + c] : 0.f;
  P[idx] = (_Float16)v;
}

__global__ __launch_bounds__(256) void pack_all_kernel(
    const float* __restrict__ W1, const float* __restrict__ W2,
    const float* __restrict__ W3, _Float16* __restrict__ P1,
    _Float16* __restrict__ P2, _Float16* __restrict__ P3, int* __restrict__ bcur) {
  int blk = blockIdx.x, t = threadIdx.x;
  if (blk < 32) {
    pack_one<128, 64, 4, 4>(W1, P1, blk * 256 + t);
  } else if (blk < 48) {
    pack_one<64, 64, 4, 2>(W2, P2, (blk - 32) * 256 + t);
  } else if (blk < 60) {
    pack_one<64, 40, 3, 2>(W3, P3, (blk - 48) * 256 + t);
  } else {
    bcur[t] = 0;
    bcur[t + 256] = 0;
  }
}

// ---------------- layer-1 MFMA GEMM (fp32 in, fp16 out, dinv pre-scale) -----

template <int K, int M, int CT>
__global__ __launch_bounds__(256) void gemm_mfma_f32in(const float* __restrict__ x,
                                                       const _Float16* __restrict__ PW,
                                                       const float* __restrict__ dinv,
                                                       _Float16* __restrict__ out, int n) {
  constexpr int KT = K / 32;
  int lane = threadIdx.x & 63, wv = threadIdx.x >> 6;
  int m = lane & 15, q = lane >> 4;
  int row0w = blockIdx.x * 64 + wv * 16;
  int arow = row0w + m;
  int ar = arow < n ? arow : n - 1;  // clamp; stores are guarded
  const half8* pw = (const half8*)PW;

  float4v acc[CT];
#pragma unroll
  for (int ct = 0; ct < CT; ct++) acc[ct] = (float4v){0.f, 0.f, 0.f, 0.f};

#pragma unroll
  for (int kt = 0; kt < KT; kt++) {
    const float* xp = x + (size_t)ar * K + kt * 32 + q * 8;
    float4 x0 = *(const float4*)xp;
    float4 x1 = *(const float4*)(xp + 4);
    half8 a;
    a[0] = (_Float16)x0.x; a[1] = (_Float16)x0.y;
    a[2] = (_Float16)x0.z; a[3] = (_Float16)x0.w;
    a[4] = (_Float16)x1.x; a[5] = (_Float16)x1.y;
    a[6] = (_Float16)x1.z; a[7] = (_Float16)x1.w;
#pragma unroll
    for (int ct = 0; ct < CT; ct++) {
      half8 b = pw[(ct * KT + kt) * 64 + lane];
      acc[ct] = __builtin_amdgcn_mfma_f32_16x16x32_f16(a, b, acc[ct], 0, 0, 0);
    }
  }
  // D layout: col = lane&15, row = q*4 + reg
  int r0 = row0w + q * 4;
  float dv[4];
#pragma unroll
  for (int reg = 0; reg < 4; reg++) dv[reg] = (r0 + reg < n) ? dinv[r0 + reg] : 0.f;
#pragma unroll
  for (int ct = 0; ct < CT; ct++) {
    int c = ct * 16 + m;
    if (c < M) {
#pragma unroll
      for (int reg = 0; reg < 4; reg++) {
        int r = r0 + reg;
        if (r < n) out[(size_t)r * M + c] = (_Float16)(acc[ct][reg] * dv[reg]);
      }
    }
  }
}

// ---------------- aggregation: dest-exclusive 8-lane groups, batch-8 MLP -----
// Block = 512 threads = 64 groups; group g EXCLUSIVELY owns dest base+g and
// its whole (contiguous, dest-sorted) csr run. Hot loop per batch of 8 edges:
// 8 independent csr loads (group-broadcast address) + 8 independent uint4
// gathers (u[0..7] live in regs -> 8 outstanding/lane) + adds. No atomics,
// no shfl, no branches -> deep MLP. Epilogue fully in registers (group owns
// the row): self-loop + dinv/bias/relu, then one 16B store per lane.

__device__ __forceinline__ void h8_unpack(uint4 u, float* f) {
  __half2 h0 = *(__half2*)&u.x, h1 = *(__half2*)&u.y;
  __half2 h2 = *(__half2*)&u.z, h3 = *(__half2*)&u.w;
  float2 f0 = __half22float2(h0), f1 = __half22float2(h1);
  float2 f2 = __half22float2(h2), f3 = __half22float2(h3);
  f[0] = f0.x; f[1] = f0.y; f[2] = f1.x; f[3] = f1.y;
  f[4] = f2.x; f[5] = f2.y; f[6] = f3.x; f[7] = f3.y;
}

__device__ __forceinline__ uint4 pack_h8v(const float* o) {
  __half2 h0 = __float22half2_rn(make_float2(o[0], o[1]));
  __half2 h1 = __float22half2_rn(make_float2(o[2], o[3]));
  __half2 h2 = __float22half2_rn(make_float2(o[4], o[5]));
  __half2 h3 = __float22half2_rn(make_float2(o[6], o[7]));
  uint4 u;
  u.x = *(unsigned*)&h0;
  u.y = *(unsigned*)&h1;
  u.z = *(unsigned*)&h2;
  u.w = *(unsigned*)&h3;
  return u;
}

__device__ __forceinline__ void agg_group8(
    const uint4* __restrict__ xw4, const int* __restrict__ csr,
    int beg, int end, int fl, float* acc) {
#pragma unroll 1
  for (int b = beg; b < end; b += 8) {
    int cnt = end - b;  // group-uniform
    int r[8];
    uint4 u[8];
#pragma unroll
    for (int j = 0; j < 8; j++) r[j] = (j < cnt) ? (csr[b + j] & RMASK) : 0;
#pragma unroll
    for (int j = 0; j < 8; j++)
      if (j < cnt) u[j] = xw4[(size_t)r[j] * 8 + fl];
#pragma unroll
    for (int j = 0; j < 8; j++) {
      if (j < cnt) {
        float f[8];
        h8_unpack(u[j], f);
#pragma unroll
        for (int k = 0; k < 8; k++) acc[k] += f[k];
      }
    }
  }
}

// ---------------- standalone mid aggregation (layer-2) ----------------
// out = relu((acc+self)*di + b2) * di   (pre-scaled for the layer-3 pre-agg)

__global__ __launch_bounds__(512) void agg_mid_kernel(
    const uint4* __restrict__ xw4, const float* __restrict__ dinv,
    const int* __restrict__ csr, const int2* __restrict__ offs2,
    const float* __restrict__ bias, uint4* __restrict__ out4, int n) {
  int t = threadIdx.x;
  int g = t >> 3, fl = t & 7;
  int i = blockIdx.x * 64 + g;
  if (i >= n) return;
  int2 oe = offs2[i];  // group-broadcast load
  float di = dinv[i];
  float acc[8] = {0.f, 0.f, 0.f, 0.f, 0.f, 0.f, 0.f, 0.f};
  agg_group8(xw4, csr, oe.x, oe.y, fl, acc);
  uint4 sv = xw4[(size_t)i * 8 + fl];  // self-loop row (pre-scaled)
  float sf[8];
  h8_unpack(sv, sf);
  const float4* b4 = (const float4*)bias;
  float4 ba = b4[fl * 2], bb = b4[fl * 2 + 1];
  float o[8];
  o[0] = fmaxf((acc[0] + sf[0]) * di + ba.x, 0.f) * di;
  o[1] = fmaxf((acc[1] + sf[1]) * di + ba.y, 0.f) * di;
  o[2] = fmaxf((acc[2] + sf[2]) * di + ba.z, 0.f) * di;
  o[3] = fmaxf((acc[3] + sf[3]) * di + ba.w, 0.f) * di;
  o[4] = fmaxf((acc[4] + sf[4]) * di + bb.x, 0.f) * di;
  o[5] = fmaxf((acc[5] + sf[5]) * di + bb.y, 0.f) * di;
  o[6] = fmaxf((acc[6] + sf[6]) * di + bb.z, 0.f) * di;
  o[7] = fmaxf((acc[7] + sf[7]) * di + bb.w, 0.f) * di;
  out4[(size_t)i * 8 + fl] = pack_h8v(o);
}

// ---------------- fused aggregation + MFMA GEMM ----------------
// Group-agg straight into fp16 tileH (stride 72, 16B-aligned rows), one
// barrier, then 8 waves run the K=64 MFMA GEMM (CT columns split across the
// two wave-quads).
// FMODE 0 (layers 1->2): agg epilogue relu(acc*di + biasA); gemm out fp16 *dinv[r].
// FMODE 1 (layer 3):     agg epilogue acc*di;               gemm out fp32 + biasG.

template <int M, int CT, int FMODE>
__global__ __launch_bounds__(512) void fused_agg_gemm(
    const uint4* __restrict__ xw4, const float* __restrict__ dinv,
    const int* __restrict__ csr, const int2* __restrict__ offs2,
    const float* __restrict__ biasA, const float* __restrict__ biasG,
    const _Float16* __restrict__ PW, void* __restrict__ outp, int n) {
  constexpr int KT = 2;  // K = 64
  __shared__ _Float16 tileH[64 * 72];
  int t = threadIdx.x;
  int base = blockIdx.x * 64;
  {
    int g = t >> 3, fl = t & 7;
    int i = base + g;
    half8 h = (half8)(_Float16)0.f;
    if (i < n) {
      int2 oe = offs2[i];
      float di = dinv[i];
      float acc[8] = {0.f, 0.f, 0.f, 0.f, 0.f, 0.f, 0.f, 0.f};
      agg_group8(xw4, csr, oe.x, oe.y, fl, acc);
      uint4 sv = xw4[(size_t)i * 8 + fl];  // self-loop row (pre-scaled)
      float sf[8];
      h8_unpack(sv, sf);
#pragma unroll
      for (int k = 0; k < 8; k++) {
        float f = acc[k] + sf[k];
        f = (FMODE == 0) ? fmaxf(f * di + biasA[fl * 8 + k], 0.f) : f * di;
        h[k] = (_Float16)f;
      }
    }
    *(half8*)&tileH[g * 72 + fl * 8] = h;
  }
  __syncthreads();

  // ---- MFMA phase: 8 waves, wave-quad wq handles CT columns [co, co+ctw) ----
  int lane = t & 63, wv = t >> 6;
  int wq = wv >> 2, wr = wv & 3;
  int co = wq * 2;
  int ctw = (CT - co < 2) ? (CT - co) : 2;  // FMODE1: quad1 gets 1 tile
  int m = lane & 15, q = lane >> 4;
  int lrow = wr * 16 + m;
  const half8* pw = (const half8*)PW;
  float4v accd[2];
#pragma unroll
  for (int ct = 0; ct < 2; ct++) accd[ct] = (float4v){0.f, 0.f, 0.f, 0.f};
#pragma unroll
  for (int kt = 0; kt < KT; kt++) {
    half8 a = *(const half8*)&tileH[lrow * 72 + kt * 32 + q * 8];
#pragma unroll
    for (int ct = 0; ct < 2; ct++) {
      if (ct < ctw) {
        half8 b = pw[((co + ct) * KT + kt) * 64 + lane];
        accd[ct] = __builtin_amdgcn_mfma_f32_16x16x32_f16(a, b, accd[ct], 0, 0, 0);
      }
    }
  }
  int r0 = base + wr * 16 + q * 4;
  if (FMODE == 0) {
    _Float16* out = (_Float16*)outp;
    float dv[4];
#pragma unroll
    for (int reg = 0; reg < 4; reg++) dv[reg] = (r0 + reg < n) ? dinv[r0 + reg] : 0.f;
#pragma unroll
    for (int ct = 0; ct < 2; ct++) {
      int c = (co + ct) * 16 + m;
      if (ct < ctw && c < M) {
#pragma unroll
        for (int reg = 0; reg < 4; reg++) {
          int r = r0 + reg;
          if (r < n) out[(size_t)r * M + c] = (_Float16)(accd[ct][reg] * dv[reg]);
        }
      }
    }
  } else {
    float* out = (float*)outp;
#pragma unroll
    for (int ct = 0; ct < 2; ct++) {
      int c = (co + ct) * 16 + m;
      if (ct < ctw && c < M) {
        float bb = biasG[c];
#pragma unroll
        for (int reg = 0; reg < 4; reg++) {
          int r = r0 + reg;
          if (r < n) out[(size_t)r * M + c] = accd[ct][reg] + bb;
        }
      }
    }
  }
}

// ---------------- launcher ----------------

extern "C" void kernel_launch(void* const* d_in, const int* in_sizes, int n_in,
                              void* d_out, int out_size, void* d_ws, size_t ws_size,
                              hipStream_t stream) {
  const float* x  = (const float*)d_in[0];
  const int*   ei = (const int*)d_in[1];
  const float* W1 = (const float*)d_in[2];
  const float* b1 = (const float*)d_in[3];
  const float* W2 = (const float*)d_in[4];
  const float* b2 = (const float*)d_in[5];
  const float* W3 = (const float*)d_in[6];
  const float* b3 = (const float*)d_in[7];

  int n = in_sizes[0] / 128;
  int e = in_sizes[1] / 2;
  const int* rowA = ei;      // edge_index[0] = source
  const int* colA = ei + e;  // edge_index[1] = destination (segment id)

  int nb = (n + BD - 1) >> SH;  // buckets (<= 512)
  int meanb = e / nb;
  int cap = meanb + (meanb / 4 > 1024 ? meanb / 4 : 1024);  // >25 sigma slack
  int nch = (e + CHUNK - 1) / CHUNK;

  size_t off = 0;
  auto alloc = [&](size_t bytes) {
    void* p = (char*)d_ws + off;
    off += (bytes + 255) & ~(size_t)255;
    return p;
  };
  // bufA (n*64*4 B) also aliases the binned edge array (nb*cap*4 <= n*103 B)
  __half* bufA  = (__half*)alloc((size_t)n * 64 * 4);
  __half* bufB  = (__half*)alloc((size_t)n * 64 * 4);
  int2*  offs2  = (int2*)alloc((size_t)n * 8);
  float* dinv   = (float*)alloc((size_t)n * 4);
  int*   csr    = (int*)alloc((size_t)nb * cap * 4);
  int*   bcur   = (int*)alloc(512 * 4);
  _Float16* PW1 = (_Float16*)alloc(4 * 4 * 64 * 8 * 2);  // CT=4, KT=4
  _Float16* PW2 = (_Float16*)alloc(4 * 2 * 64 * 8 * 2);  // CT=4, KT=2
  _Float16* PW3 = (_Float16*)alloc(3 * 2 * 64 * 8 * 2);  // CT=3, KT=2
  int*   binned = (int*)bufA;  // consumed by count_place before gemm1 writes bufA
  (void)ws_size; (void)n_in; (void)out_size;

  // fused: pack all three W matrices + zero bcur (one dispatch)
  pack_all_kernel<<<61, TPB, 0, stream>>>(W1, W2, W3, PW1, PW2, PW3, bcur);
  bin_kernel<<<nch, TPB, 0, stream>>>(rowA, colA, bcur, binned, e, nb, cap);
  count_place_kernel<<<nb, 512, 0, stream>>>(binned, bcur, cap, offs2, dinv, csr, n);

  int gmf = (n + 63) / 64;  // 64 dest rows per block everywhere

  // L1 GEMM: bufA = (x @ W1) * dinv[row]
  gemm_mfma_f32in<128, 64, 4><<<gmf, TPB, 0, stream>>>(x, PW1, dinv, (_Float16*)bufA, n);
  // agg0 + gemm2 fused: bufB = (relu(L(bufA) + b1) @ W2) * dinv[row]
  fused_agg_gemm<64, 4, 0><<<gmf, 512, 0, stream>>>(
      (const uint4*)bufA, dinv, csr, offs2, b1, nullptr, PW2, bufB, n);
  // agg1: bufA = relu(L(bufB) + b2) * dinv[row]
  agg_mid_kernel<<<gmf, 512, 0, stream>>>((const uint4*)bufB, dinv, csr, offs2,
                                          b2, (uint4*)bufA, n);
  // agg2 + gemm3 fused: out = L(bufA) @ W3 + b3  (fp32)
  fused_agg_gemm<40, 3, 1><<<gmf, 512, 0, stream>>>(
      (const uint4*)bufA, dinv, csr, offs2, nullptr, b3, PW3, d_out, n);
}